// Round 1
// 273.603 us; speedup vs baseline: 1.0306x; 1.0306x over previous
//
#include <hip/hip_runtime.h>
#include <hip/hip_bf16.h>

#define Qn 2048
#define Kn 2048
#define Cin 128
#define Hn 8
#define CHn 32
#define HDn 256
#define NSPLIT 8
#define KP 68   // dbl row stride in halves: g-stride = 4*KP halves = 136 words = 8 banks mod 32

typedef __attribute__((ext_vector_type(8))) short short8;
typedef __attribute__((ext_vector_type(4))) float f32x4;

static __device__ __forceinline__ unsigned short f2bf(float f) {
    unsigned int u = __float_as_uint(f);
    u += 0x7fffu + ((u >> 16) & 1u);
    return (unsigned short)(u >> 16);
}

// ---------------------------------------------------------------------------
// K1: projections. q=(qx@Wq)/sqrt(CH)->bf16 [Q][HD]; k=kvx@Wk->bf16 [K][HD];
//     v=kvx@Wv->bf16 TRANSPOSED [HD][K]; g=sigmoid(qx@Wg+bg)->f32 [Q][HD].
// ---------------------------------------------------------------------------
__global__ __launch_bounds__(256) void proj_kernel(
    const float* __restrict__ qx, const float* __restrict__ kvx,
    const float* __restrict__ Wq, const float* __restrict__ Wk,
    const float* __restrict__ Wv, const float* __restrict__ Wg,
    const float* __restrict__ bg,
    unsigned short* __restrict__ qb, unsigned short* __restrict__ kb,
    unsigned short* __restrict__ vtb, float* __restrict__ gb)
{
    const int mat = blockIdx.y;
    const int r0 = blockIdx.x * 8;
    const int j = threadIdx.x;
    const float* A = (mat == 0 || mat == 3) ? qx : kvx;
    const float* W = (mat == 0) ? Wq : (mat == 1) ? Wk : (mat == 2) ? Wv : Wg;
    const float* Ar = A + r0 * Cin;
    float acc[8] = {0.f, 0.f, 0.f, 0.f, 0.f, 0.f, 0.f, 0.f};
    for (int c = 0; c < Cin; ++c) {
        const float w = W[c * HDn + j];
        #pragma unroll
        for (int i = 0; i < 8; ++i)
            acc[i] = fmaf(Ar[i * Cin + c], w, acc[i]);
    }
    if (mat == 0) {
        const float s = 0.17677669529663687f; // 1/sqrt(32)
        #pragma unroll
        for (int i = 0; i < 8; ++i)
            qb[(r0 + i) * HDn + j] = f2bf(acc[i] * s);
    } else if (mat == 1) {
        #pragma unroll
        for (int i = 0; i < 8; ++i)
            kb[(r0 + i) * HDn + j] = f2bf(acc[i]);
    } else if (mat == 2) {
        unsigned short tmp[8];
        #pragma unroll
        for (int i = 0; i < 8; ++i) tmp[i] = f2bf(acc[i]);
        *(short8*)(vtb + (size_t)j * Kn + r0) = *(short8*)tmp;
    } else {
        const float b = bg[j];
        #pragma unroll
        for (int i = 0; i < 8; ++i)
            gb[(r0 + i) * HDn + j] = 1.f / (1.f + __expf(-(acc[i] + b)));
    }
}

// ---------------------------------------------------------------------------
// K2: fused attention. Grid 1024 = 128 q-tiles x 8 K-splits, 512 thr = 8 waves
// (wave == head). Per 64-k tile: block cooperatively stages fp16(bias+dist)
// into LDS dbl[h][q][KP], then per-wave MFMA QK^T + no-max softmax + PV.
// No-max softmax is safe: |logit| <= |s|~1.6 + |bias|~5.2 + 1 < 8.
//
// Pipelining (this round): the two __syncthreads() are replaced by raw
// {s_waitcnt lgkmcnt(0); s_barrier} so the compiler does NOT drain vmcnt at
// the barrier — the HBM dist/bias prefetch stays in flight across the tile
// boundary. Issue order per tile is pinned to kb -> vtb -> prefetch(kt+1)
// (sched_barrier) so in-order vmcnt waits on kf/vf never force the younger
// HBM prefetch to retire. The prefetch is only waited at the next tile's
// LDS-write phase, i.e. its latency is spanned by a full tile of compute.
// Barrier safety: at both barriers every wave's LDS reads/writes are already
// lgkm-drained; the only in-flight VMEM (dv/bv) does not touch LDS.
// ---------------------------------------------------------------------------
__global__ __launch_bounds__(512, 5) void attn_kernel(
    const unsigned short* __restrict__ qb, const unsigned short* __restrict__ kb,
    const unsigned short* __restrict__ vtb,
    const float* __restrict__ bias, const float* __restrict__ dist,
    float* __restrict__ opart, float* __restrict__ lpart)
{
    __shared__ unsigned short ps[Hn][16][72]; // P round-trip, wave-local
    __shared__ _Float16 dbl[Hn * 16 * KP];    // 17408 B

    const int bx = blockIdx.x;
    const int qt = bx >> 3;
    const int sp = bx & 7;
    const int q0 = qt * 16;
    const int k00 = sp * 256;
    const int t = threadIdx.x;
    const int h = t >> 6;
    const int l = t & 63;
    const int g = l >> 4;
    const int n = l & 15;

    // staging coordinates: thread t, rep i covers (q = (t>>7)+4i, k=(t>>1)&63, hg=t&1)
    const int sk = (t >> 1) & 63;
    const int shg = t & 1;
    const int sqb = t >> 7;

    const short8 qf = *(const short8*)(qb + (q0 + n) * HDn + h * CHn + g * 8);

    f32x4 o0 = {0.f, 0.f, 0.f, 0.f};
    f32x4 o1 = {0.f, 0.f, 0.f, 0.f};
    float lacc[4] = {0.f, 0.f, 0.f, 0.f};
    unsigned short* psh = &ps[h][0][0];
    const f32x4 z = {0.f, 0.f, 0.f, 0.f};

    // prefetch tile 0
    f32x4 dv[4];
    float bv[4];
    #pragma unroll
    for (int i = 0; i < 4; ++i) {
        const int qi = q0 + sqb + 4 * i;
        dv[i] = *(const f32x4*)(dist + ((size_t)qi * Kn + k00 + sk) * Hn + 4 * shg);
        bv[i] = bias[(size_t)qi * Kn + k00 + sk];
    }

    for (int kt = 0; kt < 4; ++kt) {
        const int k0 = k00 + kt * 64;
        // barrier 1: previous tile's dbl fully consumed. lgkm drain only —
        // keep the VMEM prefetch in flight across the barrier.
        asm volatile("s_waitcnt lgkmcnt(0)\n\ts_barrier" ::: "memory");
        #pragma unroll
        for (int i = 0; i < 4; ++i) {
            const int qi = sqb + 4 * i;
            #pragma unroll
            for (int j = 0; j < 4; ++j)
                dbl[((shg * 4 + j) * 16 + qi) * KP + sk] = (_Float16)(dv[i][j] + bv[i]);
        }
        // barrier 2: dbl writes visible before any wave reads them.
        asm volatile("s_waitcnt lgkmcnt(0)\n\ts_barrier" ::: "memory");

        // Issue L2-resident K/V fragment loads FIRST (older than the HBM
        // prefetch in vmcnt order), consume them later in the tile.
        short8 kf[4];
        #pragma unroll
        for (int kkg = 0; kkg < 4; ++kkg)
            kf[kkg] = *(const short8*)(kb + (k0 + kkg * 16 + n) * HDn + h * CHn + g * 8);
        short8 vf[4];
        #pragma unroll
        for (int chunk = 0; chunk < 2; ++chunk) {
            vf[chunk * 2]     = *(const short8*)(vtb + (h * CHn + n) * Kn + k0 + chunk * 32 + g * 8);
            vf[chunk * 2 + 1] = *(const short8*)(vtb + (h * CHn + 16 + n) * Kn + k0 + chunk * 32 + g * 8);
        }
        __builtin_amdgcn_sched_barrier(0); // pin: kf/vf issue before dv prefetch
        if (kt < 3) { // HBM prefetch for next tile; stays in flight under compute
            #pragma unroll
            for (int i = 0; i < 4; ++i) {
                const int qi = q0 + sqb + 4 * i;
                dv[i] = *(const f32x4*)(dist + ((size_t)qi * Kn + k0 + 64 + sk) * Hn + 4 * shg);
                bv[i] = bias[(size_t)qi * Kn + k0 + 64 + sk];
            }
        }

        // scores (waits kf only: vmcnt leaves vf + dv outstanding)
        f32x4 sf[4];
        #pragma unroll
        for (int kkg = 0; kkg < 4; ++kkg)
            sf[kkg] = __builtin_amdgcn_mfma_f32_16x16x32_bf16(qf, kf[kkg], z, 0, 0, 0);
        // p = exp(s + db); accumulate row sums per-lane
        const _Float16* dbh = dbl + h * 16 * KP;
        #pragma unroll
        for (int kkg = 0; kkg < 4; ++kkg) {
            #pragma unroll
            for (int r = 0; r < 4; ++r) {
                const float db = (float)dbh[(g * 4 + r) * KP + kkg * 16 + n];
                const float p = __expf(sf[kkg][r] + db);
                sf[kkg][r] = p;
                lacc[r] += p;
            }
        }
        // P: D-layout -> LDS bf16 (wave-local)
        #pragma unroll
        for (int kkg = 0; kkg < 4; ++kkg) {
            #pragma unroll
            for (int r = 0; r < 4; ++r)
                psh[(g * 4 + r) * 72 + kkg * 16 + n] = f2bf(sf[kkg][r]);
        }
        // PV (waits vf: older than dv prefetch, so dv stays in flight)
        #pragma unroll
        for (int chunk = 0; chunk < 2; ++chunk) {
            const short8 pf = *(const short8*)(psh + n * 72 + chunk * 32 + g * 8);
            o0 = __builtin_amdgcn_mfma_f32_16x16x32_bf16(pf, vf[chunk * 2], o0, 0, 0, 0);
            o1 = __builtin_amdgcn_mfma_f32_16x16x32_bf16(pf, vf[chunk * 2 + 1], o1, 0, 0, 0);
        }
    }
    // write partial O and row-sums
    float* op = opart + (size_t)sp * (Qn * HDn);
    #pragma unroll
    for (int r = 0; r < 4; ++r) {
        const int qg = q0 + g * 4 + r;
        op[qg * HDn + h * CHn + n] = o0[r];
        op[qg * HDn + h * CHn + 16 + n] = o1[r];
        float v = lacc[r];
        v += __shfl_xor(v, 1);
        v += __shfl_xor(v, 2);
        v += __shfl_xor(v, 4);
        v += __shfl_xor(v, 8);
        lacc[r] = v;
    }
    if (n == 0) {
        float* lp = lpart + (size_t)sp * (Qn * Hn);
        #pragma unroll
        for (int r = 0; r < 4; ++r)
            lp[(q0 + g * 4 + r) * Hn + h] = lacc[r];
    }
}

// ---------------------------------------------------------------------------
// K3: merge splits + gating + output projection. One block per q-row.
// ---------------------------------------------------------------------------
__global__ __launch_bounds__(256) void mergeout_kernel(
    const float* __restrict__ opart, const float* __restrict__ lpart,
    const float* __restrict__ gb, const float* __restrict__ Wo,
    const float* __restrict__ bo, float* __restrict__ out)
{
    __shared__ float olds[HDn];
    __shared__ float red[4][128];
    const int q = blockIdx.x;
    const int t = threadIdx.x;
    const int h = t >> 5;
    float s = 0.f;
    #pragma unroll
    for (int sp = 0; sp < NSPLIT; ++sp)
        s += opart[(size_t)sp * (Qn * HDn) + q * HDn + t];
    float lt = 0.f;
    #pragma unroll
    for (int sp = 0; sp < NSPLIT; ++sp)
        lt += lpart[(size_t)sp * (Qn * Hn) + q * Hn + h];
    olds[t] = (s / lt) * gb[q * HDn + t];
    __syncthreads();
    const int p = t & 63;
    const int seg = t >> 6;
    float a0 = 0.f, a1 = 0.f;
    for (int c = seg * 64; c < seg * 64 + 64; ++c) {
        const float ov = olds[c];
        const float2 w = *(const float2*)(Wo + c * Cin + 2 * p);
        a0 = fmaf(ov, w.x, a0);
        a1 = fmaf(ov, w.y, a1);
    }
    red[seg][2 * p] = a0;
    red[seg][2 * p + 1] = a1;
    __syncthreads();
    if (t < 128)
        out[q * Cin + t] = red[0][t] + red[1][t] + red[2][t] + red[3][t] + bo[t];
}

extern "C" void kernel_launch(void* const* d_in, const int* in_sizes, int n_in,
                              void* d_out, int out_size, void* d_ws, size_t ws_size,
                              hipStream_t stream)
{
    const float* qx   = (const float*)d_in[0];
    const float* kvx  = (const float*)d_in[1];
    const float* bias = (const float*)d_in[2];
    const float* dist = (const float*)d_in[3];
    const float* Wq   = (const float*)d_in[4];
    const float* Wk   = (const float*)d_in[5];
    const float* Wv   = (const float*)d_in[6];
    const float* Wg   = (const float*)d_in[7];
    const float* bg   = (const float*)d_in[8];
    const float* Wo   = (const float*)d_in[9];
    const float* bo   = (const float*)d_in[10];
    float* out = (float*)d_out;

    char* w = (char*)d_ws;
    unsigned short* qb  = (unsigned short*)(w);                  // 1 MB
    unsigned short* kb  = (unsigned short*)(w + (1ull << 20));   // 1 MB
    unsigned short* vtb = (unsigned short*)(w + (2ull << 20));   // 1 MB
    float* gb    = (float*)(w + (3ull << 20));                   // 2 MB
    float* opart = (float*)(w + (5ull << 20));                   // 16 MB (8 splits)
    float* lpart = (float*)(w + (21ull << 20));                  // 512 KB

    proj_kernel<<<dim3(Qn / 8, 4), 256, 0, stream>>>(qx, kvx, Wq, Wk, Wv, Wg, bg, qb, kb, vtb, gb);
    attn_kernel<<<dim3(128 * NSPLIT), 512, 0, stream>>>(qb, kb, vtb, bias, dist, opart, lpart);
    mergeout_kernel<<<dim3(Qn), 256, 0, stream>>>(opart, lpart, gb, Wo, bo, out);
}